// Round 5
// baseline (190.949 us; speedup 1.0000x reference)
//
#include <hip/hip_runtime.h>

// OneDilate: out[b,c,i,j] = 50 - 0.5 * sum_{10x10 clamped window} x
// Register-streaming separable box filter, no LDS/barriers.
// Thread owns 4 consecutive output cols x 16-row band.
// Fully-unrolled 25-row stream with explicit next-row prefetch registers
// (software pipeline) so loads for row s+1 are in flight during H(s).

#define IMG 512
#define OUTW 511
#define KS 10
#define MEAN 4
#define ROWS 32                      // output rows per block
#define SUBROWS 16                   // output rows per thread
#define TSTREAM (SUBROWS + KS - 1)   // 25 streamed input rows

__global__ __launch_bounds__(256) void onedilate_kernel(
    const float* __restrict__ x, float* __restrict__ out)
{
    const int tid = threadIdx.x;
    const int j   = tid & 127;           // col group: output cols 4j..4j+3
    const int sub = tid >> 7;            // 0/1 (wave-uniform)
    const int rb  = blockIdx.x * ROWS + sub * SUBROWS;  // output row base
    const int bc  = blockIdx.y;          // b*C + c

    const float* __restrict__ xim = x + (size_t)bc * IMG * IMG;
    float* __restrict__ oim = out + (size_t)bc * OUTW * OUTW;

    // Column window: 3 aligned float4 + 1 scalar cover cols 4j-4 .. 4j+8.
    const int b0  = 4 * j - 4;
    const int bl0 = max(b0, 0);
    const int b2  = 4 * j + 4;
    const int bl2 = min(b2, IMG - 4);
    const bool lo0 = (b0 < 0);               // only j==0
    const bool hi2 = (b2 > IMG - 4);         // only j==127
    const int c12 = min(4 * j + 8, IMG - 1);
    const int cbase = 4 * j;

    float4 ring[KS];
    float4 V = make_float4(0.f, 0.f, 0.f, 0.f);

    // --- software pipeline: prime with row 0 ---
    {
        const int ri0 = min(max(rb - MEAN, 0), IMG - 1);
        const float* rp = xim + ri0 * IMG;
        float4 c0 = *(const float4*)(rp + bl0);
        float4 c1 = *(const float4*)(rp + cbase);
        float4 c2 = *(const float4*)(rp + bl2);
        float cw  = rp[c12];

        #pragma unroll
        for (int s = 0; s < TSTREAM; ++s) {
            // prefetch row s+1 (static guard under full unroll)
            float4 n0, n1, n2; float nw;
            if (s + 1 < TSTREAM) {
                int ri = min(max(rb + s + 1 - MEAN, 0), IMG - 1);
                const float* np = xim + ri * IMG;
                n0 = *(const float4*)(np + bl0);
                n1 = *(const float4*)(np + cbase);
                n2 = *(const float4*)(np + bl2);
                nw = np[c12];
            }

            // horizontal sliding 10-sums for 4 outputs
            float4 a0 = c0, a2 = c2;
            if (lo0) a0 = make_float4(c0.x, c0.x, c0.x, c0.x);
            if (hi2) a2 = make_float4(c2.w, c2.w, c2.w, c2.w);
            float S = a0.x + a0.y + a0.z + a0.w
                    + c1.x + c1.y + c1.z + c1.w
                    + a2.x + a2.y;
            float4 H;
            H.x = S;
            S += a2.z - a0.x; H.y = S;
            S += a2.w - a0.y; H.z = S;
            S += cw  - a0.z;  H.w = S;

            // vertical running sum over last 10 H's
            if (s >= KS) {                  // static index under unroll
                const float4 old = ring[s % KS];
                V.x -= old.x; V.y -= old.y; V.z -= old.z; V.w -= old.w;
            }
            V.x += H.x; V.y += H.y; V.z += H.z; V.w += H.w;
            ring[s % KS] = H;

            if (s >= KS - 1) {
                int i = rb + s - (KS - 1);
                if (i < OUTW) {
                    float* op = oim + (size_t)i * OUTW + cbase;
                    op[0] = 50.0f - 0.5f * V.x;
                    op[1] = 50.0f - 0.5f * V.y;
                    op[2] = 50.0f - 0.5f * V.z;
                    if (cbase + 3 < OUTW) op[3] = 50.0f - 0.5f * V.w;
                }
            }

            if (s + 1 < TSTREAM) { c0 = n0; c1 = n1; c2 = n2; cw = nw; }
        }
    }
}

extern "C" void kernel_launch(void* const* d_in, const int* in_sizes, int n_in,
                              void* d_out, int out_size, void* d_ws, size_t ws_size,
                              hipStream_t stream) {
    const float* x = (const float*)d_in[0];
    float* out = (float*)d_out;

    dim3 block(256, 1, 1);
    dim3 grid((OUTW + ROWS - 1) / ROWS,   // 16 row bands of 32
              32 * 3,                     // 96 images
              1);
    onedilate_kernel<<<grid, block, 0, stream>>>(x, out);
}